// Round 7
// baseline (410.163 us; speedup 1.0000x reference)
//
#include <hip/hip_runtime.h>
#include <hip/hip_bf16.h>

#define N_TOK 8192
#define DIN   1024
#define DOUT  1024
#define NE    8
#define KTOT  (NE * DIN)          // 8192
#define BM    256
#define BN    128
#define NKC   (DIN / 32)          // 32 phases; phase = k-chunk of 32 across ALL 8 experts

typedef __attribute__((ext_vector_type(4))) float f32x4;
typedef __attribute__((ext_vector_type(8))) short short8;
typedef unsigned int u32;

__device__ __forceinline__ ushort f2bf(float f) {
    u32 u = __float_as_uint(f);
    u32 r = (u + 0x7fffu + ((u >> 16) & 1u)) >> 16;   // round-to-nearest-even
    return (ushort)r;
}

__device__ __forceinline__ void gload_lds16(const void* gp, void* lp) {
    __builtin_amdgcn_global_load_lds(
        (const __attribute__((address_space(1))) u32*)gp,
        (__attribute__((address_space(3))) u32*)lp, 16, 0, 0);
}

#define PH_BAR()  __builtin_amdgcn_s_barrier()
#define LGKM0()   asm volatile("s_waitcnt lgkmcnt(0)" ::: "memory")
#define VMCNT0()  asm volatile("s_waitcnt vmcnt(0)" ::: "memory")
#define SBAR0()   __builtin_amdgcn_sched_barrier(0)

// ---------------- gating: softmax(x @ Wg + bg) -> g [N_TOK][NE] (f32) -----------
__global__ void gate_kernel(const float* __restrict__ x, const float* __restrict__ Wg,
                            const float* __restrict__ bg, float* __restrict__ g) {
    int w = threadIdx.x >> 6, lane = threadIdx.x & 63;
    int n = blockIdx.x * 4 + w;
    const float* xr = x + (size_t)n * DIN;
    float p[NE];
#pragma unroll
    for (int e = 0; e < NE; ++e) p[e] = 0.f;
    for (int i = lane; i < DIN; i += 64) {
        float xv = xr[i];
        const float* wr_ = Wg + i * NE;
#pragma unroll
        for (int e = 0; e < NE; ++e) p[e] = fmaf(xv, wr_[e], p[e]);
    }
#pragma unroll
    for (int off = 32; off > 0; off >>= 1) {
#pragma unroll
        for (int e = 0; e < NE; ++e) p[e] += __shfl_down(p[e], off);
    }
    if (lane == 0) {
        float l2[NE], m = -1e30f;
#pragma unroll
        for (int e = 0; e < NE; ++e) { l2[e] = p[e] + bg[e]; m = fmaxf(m, l2[e]); }
        float s = 0.f;
#pragma unroll
        for (int e = 0; e < NE; ++e) { l2[e] = expf(l2[e] - m); s += l2[e]; }
        float inv = 1.f / s;
#pragma unroll
        for (int e = 0; e < NE; ++e) g[n * NE + e] = l2[e] * inv;
    }
}

// ---------------- x (f32) -> xb (bf16) ------------------------------------------
__global__ void cvt_x_kernel(const float* __restrict__ x, ushort* __restrict__ xb) {
    int idx = blockIdx.x * 256 + threadIdx.x;
    float4 v = ((const float4*)x)[idx];
    ushort4 o = make_ushort4(f2bf(v.x), f2bf(v.y), f2bf(v.z), f2bf(v.w));
    ((ushort4*)xb)[idx] = o;
}

// ---------------- We [8192][1024] f32 -> BT [1024][8192] bf16 (transposed) ------
__global__ void transpose_w_kernel(const float* __restrict__ We, ushort* __restrict__ BT) {
    __shared__ float tile[64][65];
    int kb = blockIdx.x * 64, ob = blockIdx.y * 64;
    int t = threadIdx.x;
#pragma unroll
    for (int ph = 0; ph < 16; ++ph) {
        int idx = ph * 256 + t;
        int r = idx >> 6, c = idx & 63;
        tile[r][c] = We[(size_t)(kb + r) * DOUT + ob + c];
    }
    __syncthreads();
#pragma unroll
    for (int ph = 0; ph < 16; ++ph) {
        int idx = ph * 256 + t;
        int r = idx >> 6, c = idx & 63;
        BT[(size_t)(ob + r) * KTOT + kb + c] = f2bf(tile[c][r]);
    }
}

// ---------------- fused MoE GEMM: expert-inner, A-frag reuse, f32 gate fold ------
// Phase s (k-chunk of 32): read 4 A-frags ONCE, then for e=0..7: read 4 B-frags,
// 16 MFMA (operands SWAPPED: mfma(B,A) so each lane's output column is one token),
// fold accF[mc][n] += g[token][e] * accP in f32 (gates live in 32 registers).
// Ring-2 LDS (A 2x16KB + B 2x64KB = 160KB); staging issued a FULL phase ahead.
__global__ __launch_bounds__(512, 2) void moe_gemm(
    const ushort* __restrict__ xb,   // [8192][1024] bf16
    const ushort* __restrict__ BT,   // [1024][8192] bf16 (o-major, k-minor)
    const float*  __restrict__ g,    // [8192][8]
    const float*  __restrict__ be,   // [8][1024]
    float*        __restrict__ out)  // [8192][1024]
{
    __shared__ __align__(16) ushort Al[2][BM * 32];        //  32 KB
    __shared__ __align__(16) ushort Bl[2][NE * BN * 32];   // 128 KB

    int bid = blockIdx.x;
    int swz = (bid & 7) * 32 + (bid >> 3);      // XCD row-slab swizzle (proven)
    int colb = swz & 7;
    int rowb = swz >> 3;
    int brow = rowb * BM, bcol = colb * BN;

    int tid = threadIdx.x;
    int w = tid >> 6, lane = tid & 63;
    int wm = w >> 1, wn = w & 1;                 // 4x2 wave grid, 64x64 per wave
    int ro = lane & 15, gq = lane >> 4;

    // gate probs -> registers: g_reg[n][e] for this lane's 4 token rows
    float g_reg[4][NE];
#pragma unroll
    for (int n = 0; n < 4; ++n) {
        int tkn = brow + wm * 64 + n * 16 + ro;
        float4 t0 = *(const float4*)&g[(size_t)tkn * NE + 0];
        float4 t1 = *(const float4*)&g[(size_t)tkn * NE + 4];
        g_reg[n][0] = t0.x; g_reg[n][1] = t0.y; g_reg[n][2] = t0.z; g_reg[n][3] = t0.w;
        g_reg[n][4] = t1.x; g_reg[n][5] = t1.y; g_reg[n][6] = t1.z; g_reg[n][7] = t1.w;
    }

    // fragment read offsets (elements), T2 XOR-swizzled
    int offA[4], offBc[4];
#pragma unroll
    for (int n = 0; n < 4; ++n) {
        int r = wm * 64 + n * 16 + ro;
        offA[n] = r * 32 + ((gq * 8) ^ ((r & 6) << 2));
    }
#pragma unroll
    for (int mc = 0; mc < 4; ++mc) {
        int c = wn * 64 + mc * 16 + ro;
        offBc[mc] = c * 32 + ((gq * 8) ^ ((c & 6) << 2));
    }

    // staging: A = 2 loads/thread (16KB), B = 8 loads/thread (64KB: L == expert)
    auto stA = [&](int buf, int s) {
#pragma unroll
        for (int L = 0; L < 2; ++L) {
            int q = L * 512 + tid;
            int row = q >> 2, slot = q & 3;
            int ks = (slot * 8) ^ ((row & 6) << 2);
            gload_lds16(xb + (size_t)(brow + row) * DIN + s * 32 + ks,
                        (char*)&Al[buf][0] + (size_t)(q & ~63) * 16);
        }
    };
    auto stB = [&](int buf, int s) {
#pragma unroll
        for (int L = 0; L < NE; ++L) {
            int q = L * 512 + tid;
            int col = (q >> 2) & 127, slot = q & 3;
            int ks = (slot * 8) ^ ((col & 6) << 2);
            gload_lds16(BT + (size_t)(bcol + col) * KTOT + L * DIN + s * 32 + ks,
                        (char*)&Bl[buf][0] + (size_t)(q & ~63) * 16);
        }
    };

    f32x4 accF[4][4];       // [mc][n], f32 gate-weighted running sum
    f32x4 accPa[4], accPb[4];
    short8 fA[4], fB[4];
#pragma unroll
    for (int mc = 0; mc < 4; ++mc)
#pragma unroll
        for (int n = 0; n < 4; ++n) accF[mc][n] = (f32x4){0.f, 0.f, 0.f, 0.f};

#define MFMA_MC(ACC, MC) do {                                                  \
    _Pragma("unroll") for (int _n = 0; _n < 4; ++_n)                           \
        ACC[_n] = __builtin_amdgcn_mfma_f32_16x16x32_bf16(                     \
            fB[MC], fA[_n], (f32x4){0.f, 0.f, 0.f, 0.f}, 0, 0, 0);             \
} while (0)
#define FOLD_MC(ACC, MC, E) do {                                               \
    _Pragma("unroll") for (int _n = 0; _n < 4; ++_n)                           \
        accF[MC][_n] += g_reg[_n][E] * ACC[_n];                                \
} while (0)

    // prologue: stage phase 0, wait, barrier
    stA(0, 0); stB(0, 0);
    VMCNT0();
    PH_BAR();

    for (int s = 0; s < NKC; ++s) {
        const ushort* Ab = &Al[s & 1][0];
        const ushort* Bb = &Bl[s & 1][0];

        // phase-start LDS reads: A frags (reused by all 8 experts) + B frags e=0
#pragma unroll
        for (int n = 0; n < 4; ++n) fA[n] = *(const short8*)(Ab + offA[n]);
#pragma unroll
        for (int mc = 0; mc < 4; ++mc) fB[mc] = *(const short8*)(Bb + offBc[mc]);

        // issue next phase's staging NOW: a full phase (~5000 cyc) of latency cover
        if (s < NKC - 1) { stA((s + 1) & 1, s + 1); stB((s + 1) & 1, s + 1); }

#pragma unroll
        for (int e = 0; e < NE; ++e) {
            LGKM0(); SBAR0();          // rule #18: pin MFMAs below the wait
            __builtin_amdgcn_s_setprio(1);
            MFMA_MC(accPa, 0);
            MFMA_MC(accPb, 1);
            FOLD_MC(accPa, 0, e);
            MFMA_MC(accPa, 2);
            FOLD_MC(accPb, 1, e);
            MFMA_MC(accPb, 3);
            __builtin_amdgcn_s_setprio(0);
            if (e < NE - 1) {          // B frags for next expert (ds-latency hidden by folds)
#pragma unroll
                for (int mc = 0; mc < 4; ++mc)
                    fB[mc] = *(const short8*)(Bb + (e + 1) * (BN * 32) + offBc[mc]);
            }
            FOLD_MC(accPa, 2, e);
            FOLD_MC(accPb, 3, e);
        }

        VMCNT0();      // next phase's staging done (issued ~full phase ago -> ~free)
        PH_BAR();
    }

#undef MFMA_MC
#undef FOLD_MC

    // epilogue: out[tkn][col] = accF + sum_e g_e * be[e][col]   (float4 stores)
#pragma unroll
    for (int mc = 0; mc < 4; ++mc) {
        int cb = bcol + wn * 64 + mc * 16 + gq * 4;
        f32x4 bev[NE];
#pragma unroll
        for (int e = 0; e < NE; ++e) bev[e] = *(const f32x4*)&be[e * DOUT + cb];
#pragma unroll
        for (int n = 0; n < 4; ++n) {
            f32x4 v = accF[mc][n];
#pragma unroll
            for (int e = 0; e < NE; ++e) v += g_reg[n][e] * bev[e];
            int tkn = brow + wm * 64 + n * 16 + ro;
            *(f32x4*)&out[(size_t)tkn * DOUT + cb] = v;
        }
    }
}

extern "C" void kernel_launch(void* const* d_in, const int* in_sizes, int n_in,
                              void* d_out, int out_size, void* d_ws, size_t ws_size,
                              hipStream_t stream) {
    const float* x  = (const float*)d_in[0];
    const float* We = (const float*)d_in[1];
    const float* be = (const float*)d_in[2];
    const float* Wg = (const float*)d_in[3];
    const float* bg = (const float*)d_in[4];
    float* out = (float*)d_out;

    char* ws = (char*)d_ws;
    float*  gbuf = (float*)ws;                                       // 256 KB
    ushort* xb   = (ushort*)(ws + (size_t)256 * 1024);               // 16 MB
    ushort* BT   = (ushort*)(ws + (size_t)256 * 1024 + (size_t)N_TOK * DIN * 2); // 16 MB

    gate_kernel<<<N_TOK / 4, 256, 0, stream>>>(x, Wg, bg, gbuf);
    cvt_x_kernel<<<(N_TOK * DIN / 4) / 256, 256, 0, stream>>>(x, xb);
    transpose_w_kernel<<<dim3(KTOT / 64, DOUT / 64), 256, 0, stream>>>(We, BT);
    moe_gemm<<<(N_TOK / BM) * (DOUT / BN), 512, 0, stream>>>(xb, BT, gbuf, be, out);
}

// Round 8
// 350.613 us; speedup vs baseline: 1.1698x; 1.1698x over previous
//
#include <hip/hip_runtime.h>
#include <hip/hip_bf16.h>

#define N_TOK 8192
#define DIN   1024
#define DOUT  1024
#define NE    8
#define KTOT  (NE * DIN)          // 8192
#define BM    256
#define BN    128
#define NKH   (KTOT / 32)         // 256 phases (k=32 each)

typedef __attribute__((ext_vector_type(4))) float f32x4;
typedef __attribute__((ext_vector_type(8))) short short8;
typedef unsigned int u32;

__device__ __forceinline__ ushort f2bf(float f) {
    u32 u = __float_as_uint(f);
    u32 r = (u + 0x7fffu + ((u >> 16) & 1u)) >> 16;   // round-to-nearest-even
    return (ushort)r;
}

__device__ __forceinline__ void gload_lds16(const void* gp, void* lp) {
    __builtin_amdgcn_global_load_lds(
        (const __attribute__((address_space(1))) u32*)gp,
        (__attribute__((address_space(3))) u32*)lp, 16, 0, 0);
}

#define PH_BAR()  __builtin_amdgcn_s_barrier()
#define LGKM0()   asm volatile("s_waitcnt lgkmcnt(0)" ::: "memory")
#define LGKM4()   asm volatile("s_waitcnt lgkmcnt(4)" ::: "memory")
#define VMCNT6()  asm volatile("s_waitcnt vmcnt(6)" ::: "memory")
#define VMCNT4()  asm volatile("s_waitcnt vmcnt(4)" ::: "memory")
#define VMCNT0()  asm volatile("s_waitcnt vmcnt(0)" ::: "memory")
#define SBAR0()   __builtin_amdgcn_sched_barrier(0)

// ---------------- gating: softmax(x @ Wg + bg) -> g [N_TOK][NE] (f32) -----------
__global__ void gate_kernel(const float* __restrict__ x, const float* __restrict__ Wg,
                            const float* __restrict__ bg, float* __restrict__ g) {
    int w = threadIdx.x >> 6, lane = threadIdx.x & 63;
    int n = blockIdx.x * 4 + w;
    const float* xr = x + (size_t)n * DIN;
    float p[NE];
#pragma unroll
    for (int e = 0; e < NE; ++e) p[e] = 0.f;
    for (int i = lane; i < DIN; i += 64) {
        float xv = xr[i];
        const float* wr_ = Wg + i * NE;
#pragma unroll
        for (int e = 0; e < NE; ++e) p[e] = fmaf(xv, wr_[e], p[e]);
    }
#pragma unroll
    for (int off = 32; off > 0; off >>= 1) {
#pragma unroll
        for (int e = 0; e < NE; ++e) p[e] += __shfl_down(p[e], off);
    }
    if (lane == 0) {
        float l2[NE], m = -1e30f;
#pragma unroll
        for (int e = 0; e < NE; ++e) { l2[e] = p[e] + bg[e]; m = fmaxf(m, l2[e]); }
        float s = 0.f;
#pragma unroll
        for (int e = 0; e < NE; ++e) { l2[e] = expf(l2[e] - m); s += l2[e]; }
        float inv = 1.f / s;
#pragma unroll
        for (int e = 0; e < NE; ++e) g[n * NE + e] = l2[e] * inv;
    }
}

// ---------------- x (f32) -> xb (bf16) ------------------------------------------
__global__ void cvt_x_kernel(const float* __restrict__ x, ushort* __restrict__ xb) {
    int idx = blockIdx.x * 256 + threadIdx.x;
    float4 v = ((const float4*)x)[idx];
    ushort4 o = make_ushort4(f2bf(v.x), f2bf(v.y), f2bf(v.z), f2bf(v.w));
    ((ushort4*)xb)[idx] = o;
}

// ---------------- We [8192][1024] f32 -> BT [1024][8192] bf16 (transposed) ------
__global__ void transpose_w_kernel(const float* __restrict__ We, ushort* __restrict__ BT) {
    __shared__ float tile[64][65];
    int kb = blockIdx.x * 64, ob = blockIdx.y * 64;
    int t = threadIdx.x;
#pragma unroll
    for (int ph = 0; ph < 16; ++ph) {
        int idx = ph * 256 + t;
        int r = idx >> 6, c = idx & 63;
        tile[r][c] = We[(size_t)(kb + r) * DOUT + ob + c];
    }
    __syncthreads();
#pragma unroll
    for (int ph = 0; ph < 16; ++ph) {
        int idx = ph * 256 + t;
        int r = idx >> 6, c = idx & 63;
        BT[(size_t)(ob + r) * KTOT + kb + c] = f2bf(tile[c][r]);
    }
}

// ---------------- fused MoE GEMM: A via LDS ring-4, B DIRECT global->reg ---------
// Phase k: {4 ds_read A-frags for k+1} {2 gload_lds A ring k+3} -> lgkm(4) ->
// sched_barrier -> 16 MFMA(fA[k],bReg[k]) -> issue B(k+2) (reg dbuf, WAR-safe
// after MFMA) -> [fold at expert boundary] -> vmcnt(6) -> barrier.
// B never touches LDS: each wave global-loads its 4 B-frags (16B k-contiguous,
// identical bytes to the old staged tile); 4-wave duplication hits L1.
__global__ __launch_bounds__(512, 2) void moe_gemm(
    const ushort* __restrict__ xb,   // [8192][1024] bf16
    const ushort* __restrict__ BT,   // [1024][8192] bf16 (o-major, k-minor)
    const float*  __restrict__ g,    // [8192][8]
    const float*  __restrict__ be,   // [8][1024]
    float*        __restrict__ out)  // [8192][1024]
{
    __shared__ __align__(16) ushort Al[4][BM * 32];   // 64 KB ring (A only)
    __shared__ __align__(16) float  gLds[BM][NE];     //  8 KB

    int bid = blockIdx.x;
    int swz = (bid & 7) * 32 + (bid >> 3);      // XCD row-slab swizzle (proven)
    int colb = swz & 7;
    int rowb = swz >> 3;
    int brow = rowb * BM, bcol = colb * BN;

    int tid = threadIdx.x;
    int w = tid >> 6, lane = tid & 63;
    int wm = w >> 1, wn = w & 1;                 // 4x2 wave grid, 64x64 per wave
    int ro = lane & 15, gq = lane >> 4;
    int jrow = gq * 4;

    // gate probs -> LDS
    float4 gv = ((const float4*)(g + (size_t)brow * NE))[tid];
    ((float4*)&gLds[0][0])[tid] = gv;

    // A fragment read offsets (T2-swizzled)
    int offA[4];
#pragma unroll
    for (int m = 0; m < 4; ++m) {
        int r = wm * 64 + m * 16 + ro;
        offA[m] = r * 32 + ((gq * 8) ^ ((r & 6) << 2));
    }
    // B per-lane global base pointers (col-major rows of BT, k-minor)
    const ushort* bBase[4];
#pragma unroll
    for (int n = 0; n < 4; ++n) {
        int c = bcol + wn * 64 + n * 16 + ro;
        bBase[n] = BT + (size_t)c * KTOT + gq * 8;
    }

    auto stA = [&](int s, int K) {
#pragma unroll
        for (int L = 0; L < 2; ++L) {
            int chunk = L * 512 + tid;
            int row = chunk >> 2, slot = chunk & 3;
            int ks = (slot * 8) ^ ((row & 6) << 2);
            int ka = (K * 32) & (DIN - 1);
            gload_lds16(xb + (size_t)(brow + row) * DIN + ka + ks,
                        (char*)&Al[s][0] + (size_t)(chunk & ~63) * 16);
        }
    };

    f32x4 accP[4][4];
    u32   accB[4][4][2];
    short8 fA[2][4], bReg[2][4];   // literal-indexed only
#pragma unroll
    for (int m = 0; m < 4; ++m)
#pragma unroll
        for (int n = 0; n < 4; ++n) {
            accP[m][n] = (f32x4){0.f, 0.f, 0.f, 0.f};
            accB[m][n][0] = 0u; accB[m][n][1] = 0u;
        }

    auto fold = [&](int e) {
#pragma unroll
        for (int m = 0; m < 4; ++m) {
            int rbase = wm * 64 + m * 16 + jrow;
            float g0 = gLds[rbase + 0][e], g1 = gLds[rbase + 1][e];
            float g2 = gLds[rbase + 2][e], g3 = gLds[rbase + 3][e];
#pragma unroll
            for (int n = 0; n < 4; ++n) {
                u32 p0 = accB[m][n][0];
                float lo0 = __uint_as_float(p0 << 16)         + g0 * accP[m][n][0];
                float hi0 = __uint_as_float(p0 & 0xffff0000u) + g1 * accP[m][n][1];
                accB[m][n][0] = (u32)f2bf(lo0) | ((u32)f2bf(hi0) << 16);
                u32 p1 = accB[m][n][1];
                float lo1 = __uint_as_float(p1 << 16)         + g2 * accP[m][n][2];
                float hi1 = __uint_as_float(p1 & 0xffff0000u) + g3 * accP[m][n][3];
                accB[m][n][1] = (u32)f2bf(lo1) | ((u32)f2bf(hi1) << 16);
                accP[m][n] = (f32x4){0.f, 0.f, 0.f, 0.f};
            }
        }
    };

#define LD_FRAGS(SET, RBUF) do {                                              \
    const ushort* _As = &Al[RBUF][0];                                         \
    _Pragma("unroll") for (int _m = 0; _m < 4; ++_m)                          \
        fA[SET][_m] = *(const short8*)(_As + offA[_m]);                       \
} while (0)

#define ISSUE_B(SET, KP) do {                                                 \
    _Pragma("unroll") for (int _n = 0; _n < 4; ++_n)                          \
        bReg[SET][_n] = *(const short8*)(bBase[_n] + (size_t)(KP) * 32);      \
} while (0)

#define DO_MFMA(SET) do {                                                     \
    __builtin_amdgcn_s_setprio(1);                                            \
    _Pragma("unroll") for (int _m = 0; _m < 4; ++_m) {                        \
        accP[_m][0] = __builtin_amdgcn_mfma_f32_16x16x32_bf16(fA[SET][_m], bReg[SET][0], accP[_m][0], 0, 0, 0); \
        accP[_m][1] = __builtin_amdgcn_mfma_f32_16x16x32_bf16(fA[SET][_m], bReg[SET][1], accP[_m][1], 0, 0, 0); \
        accP[_m][2] = __builtin_amdgcn_mfma_f32_16x16x32_bf16(fA[SET][_m], bReg[SET][2], accP[_m][2], 0, 0, 0); \
        accP[_m][3] = __builtin_amdgcn_mfma_f32_16x16x32_bf16(fA[SET][_m], bReg[SET][3], accP[_m][3], 0, 0, 0); \
    }                                                                         \
    __builtin_amdgcn_s_setprio(0);                                            \
} while (0)

    // prologue: A rings 0..2; B(0)->set0, B(1)->set1; wait all but B(1); frags 0
    stA(0, 0); stA(1, 1); stA(2, 2);
    ISSUE_B(0, 0); ISSUE_B(1, 1);
    VMCNT4();
    PH_BAR();
    LD_FRAGS(0, 0);

    // main loop: phases 0..251 (unroll x4: ring/set indices literal)
    for (int it = 0; it < 63; ++it) {
        int k = it * 4;
        // phase k+0
        LD_FRAGS(1, 1); stA(3, k + 3);
        LGKM4(); SBAR0(); DO_MFMA(0);
        ISSUE_B(0, k + 2);
        VMCNT6(); PH_BAR();
        // phase k+1
        LD_FRAGS(0, 2); stA(0, k + 4);
        LGKM4(); SBAR0(); DO_MFMA(1);
        ISSUE_B(1, k + 3);
        VMCNT6(); PH_BAR();
        // phase k+2
        LD_FRAGS(1, 3); stA(1, k + 5);
        LGKM4(); SBAR0(); DO_MFMA(0);
        ISSUE_B(0, k + 4);
        VMCNT6(); PH_BAR();
        // phase k+3 (fold experts 0..6 when (k+3)&31 == 31)
        LD_FRAGS(0, 0); stA(2, k + 6);
        LGKM4(); SBAR0(); DO_MFMA(1);
        ISSUE_B(1, k + 5);
        if ((it & 7) == 7) fold(it >> 3);
        VMCNT6(); PH_BAR();
    }

    // tail: phases 252..255
    LD_FRAGS(1, 1); stA(3, 255);
    LGKM4(); SBAR0(); DO_MFMA(0);
    ISSUE_B(0, 254);
    VMCNT6(); PH_BAR();                       // phase 252
    LD_FRAGS(0, 2);
    LGKM4(); SBAR0(); DO_MFMA(1);
    ISSUE_B(1, 255);
    VMCNT4(); PH_BAR();                       // phase 253
    LD_FRAGS(1, 3);
    LGKM4(); SBAR0(); DO_MFMA(0);
    VMCNT0(); PH_BAR();                       // phase 254
    LGKM0(); SBAR0(); DO_MFMA(1);             // phase 255 (expert 7 stays in accP)

#undef LD_FRAGS
#undef ISSUE_B
#undef DO_MFMA

    // epilogue: out = unpack(accB) + g7*accP + sum_e g_e*be_e
#pragma unroll
    for (int m = 0; m < 4; ++m) {
#pragma unroll
        for (int j = 0; j < 4; ++j) {
            int lrow = wm * 64 + m * 16 + jrow + j;
            int grow = brow + lrow;
            float g8[NE];
#pragma unroll
            for (int e = 0; e < NE; ++e) g8[e] = gLds[lrow][e];
#pragma unroll
            for (int n = 0; n < 4; ++n) {
                int col = bcol + wn * 64 + n * 16 + ro;
                float bias = 0.f;
#pragma unroll
                for (int e = 0; e < NE; ++e) bias = fmaf(g8[e], be[e * DOUT + col], bias);
                u32 p = accB[m][n][j >> 1];
                float base = __uint_as_float((j & 1) ? (p & 0xffff0000u) : (p << 16));
                out[(size_t)grow * DOUT + col] = base + g8[7] * accP[m][n][j] + bias;
            }
        }
    }
}

extern "C" void kernel_launch(void* const* d_in, const int* in_sizes, int n_in,
                              void* d_out, int out_size, void* d_ws, size_t ws_size,
                              hipStream_t stream) {
    const float* x  = (const float*)d_in[0];
    const float* We = (const float*)d_in[1];
    const float* be = (const float*)d_in[2];
    const float* Wg = (const float*)d_in[3];
    const float* bg = (const float*)d_in[4];
    float* out = (float*)d_out;

    char* ws = (char*)d_ws;
    float*  gbuf = (float*)ws;                                       // 256 KB
    ushort* xb   = (ushort*)(ws + (size_t)256 * 1024);               // 16 MB
    ushort* BT   = (ushort*)(ws + (size_t)256 * 1024 + (size_t)N_TOK * DIN * 2); // 16 MB

    gate_kernel<<<N_TOK / 4, 256, 0, stream>>>(x, Wg, bg, gbuf);
    cvt_x_kernel<<<(N_TOK * DIN / 4) / 256, 256, 0, stream>>>(x, xb);
    transpose_w_kernel<<<dim3(KTOT / 64, DOUT / 64), 256, 0, stream>>>(We, BT);
    moe_gemm<<<(N_TOK / BM) * (DOUT / BN), 512, 0, stream>>>(xb, BT, gbuf, be, out);
}

// Round 9
// 216.958 us; speedup vs baseline: 1.8905x; 1.6160x over previous
//
#include <hip/hip_runtime.h>
#include <hip/hip_bf16.h>

#define N_TOK 8192
#define DIN   1024
#define DOUT  1024
#define NE    8
#define KTOT  (NE * DIN)          // 8192
#define BM    256
#define BN    128

typedef __attribute__((ext_vector_type(4))) float f32x4;
typedef __attribute__((ext_vector_type(8))) short short8;
typedef unsigned int u32;

__device__ __forceinline__ ushort f2bf(float f) {
    u32 u = __float_as_uint(f);
    u32 r = (u + 0x7fffu + ((u >> 16) & 1u)) >> 16;   // round-to-nearest-even
    return (ushort)r;
}

__device__ __forceinline__ void gload_lds16(const void* gp, void* lp) {
    __builtin_amdgcn_global_load_lds(
        (const __attribute__((address_space(1))) u32*)gp,
        (__attribute__((address_space(3))) u32*)lp, 16, 0, 0);
}

#define PH_BAR()  __builtin_amdgcn_s_barrier()
#define LGKM0()   asm volatile("s_waitcnt lgkmcnt(0)" ::: "memory")
#define VMCNT6()  asm volatile("s_waitcnt vmcnt(6)" ::: "memory")
#define VMCNT3()  asm volatile("s_waitcnt vmcnt(3)" ::: "memory")
#define VMCNT0()  asm volatile("s_waitcnt vmcnt(0)" ::: "memory")

// ---------------- gating: softmax(x @ Wg + bg) -> g [N_TOK][NE] (f32) -----------
__global__ void gate_kernel(const float* __restrict__ x, const float* __restrict__ Wg,
                            const float* __restrict__ bg, float* __restrict__ g) {
    int w = threadIdx.x >> 6, lane = threadIdx.x & 63;
    int n = blockIdx.x * 4 + w;
    const float* xr = x + (size_t)n * DIN;
    float p[NE];
#pragma unroll
    for (int e = 0; e < NE; ++e) p[e] = 0.f;
    for (int i = lane; i < DIN; i += 64) {
        float xv = xr[i];
        const float* wr_ = Wg + i * NE;
#pragma unroll
        for (int e = 0; e < NE; ++e) p[e] = fmaf(xv, wr_[e], p[e]);
    }
#pragma unroll
    for (int off = 32; off > 0; off >>= 1) {
#pragma unroll
        for (int e = 0; e < NE; ++e) p[e] += __shfl_down(p[e], off);
    }
    if (lane == 0) {
        float l2[NE], m = -1e30f;
#pragma unroll
        for (int e = 0; e < NE; ++e) { l2[e] = p[e] + bg[e]; m = fmaxf(m, l2[e]); }
        float s = 0.f;
#pragma unroll
        for (int e = 0; e < NE; ++e) { l2[e] = expf(l2[e] - m); s += l2[e]; }
        float inv = 1.f / s;
#pragma unroll
        for (int e = 0; e < NE; ++e) g[n * NE + e] = l2[e] * inv;
    }
}

// ---------------- We [8192][1024] f32 -> BT [1024][8192] bf16 (transposed) ------
__global__ void transpose_w_kernel(const float* __restrict__ We, ushort* __restrict__ BT) {
    __shared__ float tile[64][65];
    int kb = blockIdx.x * 64, ob = blockIdx.y * 64;
    int t = threadIdx.x;
#pragma unroll
    for (int ph = 0; ph < 16; ++ph) {
        int idx = ph * 256 + t;
        int r = idx >> 6, c = idx & 63;
        tile[r][c] = We[(size_t)(kb + r) * DOUT + ob + c];
    }
    __syncthreads();
#pragma unroll
    for (int ph = 0; ph < 16; ++ph) {
        int idx = ph * 256 + t;
        int r = idx >> 6, c = idx & 63;
        BT[(size_t)(ob + r) * KTOT + kb + c] = f2bf(tile[c][r]);
    }
}

// ---------------- prescale: Ag[n][e*1024+i] = bf16(g[n][e] * x[n][i]) -----------
__global__ void prescale_kernel(const float* __restrict__ x, const float* __restrict__ g,
                                ushort* __restrict__ Ag) {
    int idx = blockIdx.x * 256 + threadIdx.x;   // 1M threads: n = idx>>7, c = idx&127
    int n = idx >> 7, c = idx & 127;
    float4 x0 = *(const float4*)&x[(size_t)n * DIN + c * 8];
    float4 x1 = *(const float4*)&x[(size_t)n * DIN + c * 8 + 4];
    float4 g0 = *(const float4*)&g[(size_t)n * NE + 0];
    float4 g1 = *(const float4*)&g[(size_t)n * NE + 4];
    float ge[NE] = {g0.x, g0.y, g0.z, g0.w, g1.x, g1.y, g1.z, g1.w};
#pragma unroll
    for (int e = 0; e < NE; ++e) {
        float s = ge[e];
        short8 v;
        v[0] = (short)f2bf(s * x0.x); v[1] = (short)f2bf(s * x0.y);
        v[2] = (short)f2bf(s * x0.z); v[3] = (short)f2bf(s * x0.w);
        v[4] = (short)f2bf(s * x1.x); v[5] = (short)f2bf(s * x1.y);
        v[6] = (short)f2bf(s * x1.z); v[7] = (short)f2bf(s * x1.w);
        *(short8*)&Ag[(size_t)n * KTOT + e * DIN + c * 8] = v;
    }
}

// ---------------- bias init: out[n][o] = sum_e g[n][e] * be[e][o] ---------------
__global__ void biasinit_kernel(const float* __restrict__ g, const float* __restrict__ be,
                                float* __restrict__ out) {
    int idx = blockIdx.x * 256 + threadIdx.x;   // 2M threads: n = idx>>8, o4 = idx&255
    int n = idx >> 8, o4 = (idx & 255) * 4;
    float4 g0 = *(const float4*)&g[(size_t)n * NE + 0];
    float4 g1 = *(const float4*)&g[(size_t)n * NE + 4];
    float ge[NE] = {g0.x, g0.y, g0.z, g0.w, g1.x, g1.y, g1.z, g1.w};
    f32x4 acc = (f32x4){0.f, 0.f, 0.f, 0.f};
#pragma unroll
    for (int e = 0; e < NE; ++e) {
        f32x4 b = *(const f32x4*)&be[e * DOUT + o4];
        acc += ge[e] * b;
    }
    *(f32x4*)&out[(size_t)n * DOUT + o4] = acc;
}

// ---------------- main GEMM (prescaled A): plain 8192x1024x8192 bf16 -------------
// Ring-3 LDS, counted vmcnt(3), 2 barriers/phase, VGPR<=128 -> 2 blocks/CU:
// cross-block overlap hides each block's lockstep read->MFMA serialization.
__global__ __launch_bounds__(512, 4) void moe_gemm_ps(
    const ushort* __restrict__ Ag,   // [8192][8192] bf16 (gate-prescaled fat A)
    const ushort* __restrict__ BT,   // [1024][8192] bf16
    float*        __restrict__ out)  // [8192][1024], pre-initialized with bias
{
    __shared__ __align__(16) ushort Al[3][BM * 32];   // 48 KB
    __shared__ __align__(16) ushort Bl[3][BN * 32];   // 24 KB

    int bid = blockIdx.x;
    int swz = (bid & 7) * 32 + (bid >> 3);      // XCD row-slab swizzle (proven)
    int colb = swz & 7;
    int rowb = swz >> 3;
    int brow = rowb * BM, bcol = colb * BN;

    int tid = threadIdx.x;
    int w = tid >> 6, lane = tid & 63;
    int wm = w >> 1, wn = w & 1;                 // 4x2 wave grid, 64x64 per wave
    int ro = lane & 15, gq = lane >> 4;

    // fragment read offsets (T2 XOR-swizzled)
    int offA[4], offB[4];
#pragma unroll
    for (int m = 0; m < 4; ++m) {
        int r = wm * 64 + m * 16 + ro;
        offA[m] = r * 32 + ((gq * 8) ^ ((r & 6) << 2));
    }
#pragma unroll
    for (int n = 0; n < 4; ++n) {
        int c = wn * 64 + n * 16 + ro;
        offB[n] = c * 32 + ((gq * 8) ^ ((c & 6) << 2));
    }

    // staging group K (k-chunk of 32): A = 2 chunks/thread, B = 1 chunk/thread.
    // Both operands are [row][8192] with identical addressing (fat A!).
    auto stage = [&](int s, int K) {
#pragma unroll
        for (int L = 0; L < 2; ++L) {
            int chunk = L * 512 + tid;
            int row = chunk >> 2, slot = chunk & 3;
            int ks = (slot * 8) ^ ((row & 6) << 2);
            gload_lds16(Ag + (size_t)(brow + row) * KTOT + K * 32 + ks,
                        (char*)&Al[s][0] + (size_t)(chunk & ~63) * 16);
        }
        int chunk = tid;
        int row = chunk >> 2, slot = chunk & 3;
        int ks = (slot * 8) ^ ((row & 6) << 2);
        gload_lds16(BT + (size_t)(bcol + row) * KTOT + K * 32 + ks,
                    (char*)&Bl[s][0] + (size_t)(chunk & ~63) * 16);
    };

    f32x4 accP[4][4];
#pragma unroll
    for (int m = 0; m < 4; ++m)
#pragma unroll
        for (int n = 0; n < 4; ++n) accP[m][n] = (f32x4){0.f, 0.f, 0.f, 0.f};

// one phase: read frags from BUF, optionally stage group KK+2 into SBUF,
// 16 MFMA, counted wait, barrier. WAITN: 3 = steady, 0 = drain, -1 = none.
#define PHASE(BUF, SBUF, KK, ISSUE, WAITN) do {                               \
    const ushort* _As = &Al[BUF][0];                                          \
    const ushort* _Bs = &Bl[BUF][0];                                          \
    short8 _a[4], _b[4];                                                      \
    _Pragma("unroll") for (int _m = 0; _m < 4; ++_m)                          \
        _a[_m] = *(const short8*)(_As + offA[_m]);                            \
    _Pragma("unroll") for (int _n = 0; _n < 4; ++_n)                          \
        _b[_n] = *(const short8*)(_Bs + offB[_n]);                            \
    if (ISSUE) stage(SBUF, (KK) + 2);                                         \
    __builtin_amdgcn_s_setprio(1);                                            \
    _Pragma("unroll") for (int _m = 0; _m < 4; ++_m) {                        \
        accP[_m][0] = __builtin_amdgcn_mfma_f32_16x16x32_bf16(_a[_m], _b[0], accP[_m][0], 0, 0, 0); \
        accP[_m][1] = __builtin_amdgcn_mfma_f32_16x16x32_bf16(_a[_m], _b[1], accP[_m][1], 0, 0, 0); \
        accP[_m][2] = __builtin_amdgcn_mfma_f32_16x16x32_bf16(_a[_m], _b[2], accP[_m][2], 0, 0, 0); \
        accP[_m][3] = __builtin_amdgcn_mfma_f32_16x16x32_bf16(_a[_m], _b[3], accP[_m][3], 0, 0, 0); \
    }                                                                         \
    __builtin_amdgcn_s_setprio(0);                                            \
    if ((WAITN) == 3) VMCNT3(); else if ((WAITN) == 0) VMCNT0();              \
    if ((WAITN) >= 0) PH_BAR();                                               \
} while (0)

    // prologue: stage groups 0,1; wait group 0; barrier
    stage(0, 0); stage(1, 1);
    VMCNT3();
    PH_BAR();

    // main loop: phases 0..251 (84 iters x 3: ring slot = K mod 3, literal)
    for (int it = 0; it < 84; ++it) {
        int k = it * 3;
        PHASE(0, 2, k + 0, 1, 3);
        PHASE(1, 0, k + 1, 1, 3);
        PHASE(2, 1, k + 2, 1, 3);
    }
    // tail: 252 (issues 254), 253 (issues 255), 254, 255
    PHASE(0, 2, 252, 1, 3);
    PHASE(1, 0, 253, 1, 3);
    PHASE(2, 0, 254, 0, 0);
    PHASE(0, 0, 255, 0, -1);
#undef PHASE

    // epilogue: out += accP  (out holds the bias term)
#pragma unroll
    for (int m = 0; m < 4; ++m) {
#pragma unroll
        for (int j = 0; j < 4; ++j) {
            int grow = brow + wm * 64 + m * 16 + gq * 4 + j;
#pragma unroll
            for (int n = 0; n < 4; ++n) {
                int col = bcol + wn * 64 + n * 16 + ro;
                out[(size_t)grow * DOUT + col] += accP[m][n][j];
            }
        }
    }
}

// ================= FALLBACK PATH (R4, 190us) for small ws ========================
__global__ void cvt_x_kernel(const float* __restrict__ x, ushort* __restrict__ xb) {
    int idx = blockIdx.x * 256 + threadIdx.x;
    float4 v = ((const float4*)x)[idx];
    ushort4 o = make_ushort4(f2bf(v.x), f2bf(v.y), f2bf(v.z), f2bf(v.w));
    ((ushort4*)xb)[idx] = o;
}

__global__ __launch_bounds__(512, 2) void moe_gemm_fb(
    const ushort* __restrict__ xb, const ushort* __restrict__ BT,
    const float* __restrict__ g, const float* __restrict__ be,
    float* __restrict__ out)
{
    __shared__ __align__(16) ushort Al[4][BM * 32];
    __shared__ __align__(16) ushort Bl[4][BN * 32];
    __shared__ __align__(16) float  gLds[BM][NE];

    int bid = blockIdx.x;
    int swz = (bid & 7) * 32 + (bid >> 3);
    int colb = swz & 7, rowb = swz >> 3;
    int brow = rowb * BM, bcol = colb * BN;
    int tid = threadIdx.x;
    int w = tid >> 6, lane = tid & 63;
    int wm = w >> 1, wn = w & 1;
    int ro = lane & 15, gq = lane >> 4;
    int jrow = gq * 4;

    float4 gv = ((const float4*)(g + (size_t)brow * NE))[tid];
    ((float4*)&gLds[0][0])[tid] = gv;

    int offA[4], offB[4];
#pragma unroll
    for (int m = 0; m < 4; ++m) {
        int r = wm * 64 + m * 16 + ro;
        offA[m] = r * 32 + ((gq * 8) ^ ((r & 6) << 2));
    }
#pragma unroll
    for (int n = 0; n < 4; ++n) {
        int c = wn * 64 + n * 16 + ro;
        offB[n] = c * 32 + ((gq * 8) ^ ((c & 6) << 2));
    }

    auto stA = [&](int s, int K) {
#pragma unroll
        for (int L = 0; L < 2; ++L) {
            int chunk = L * 512 + tid;
            int row = chunk >> 2, slot = chunk & 3;
            int ks = (slot * 8) ^ ((row & 6) << 2);
            int ka = (K * 32) & (DIN - 1);
            gload_lds16(xb + (size_t)(brow + row) * DIN + ka + ks,
                        (char*)&Al[s][0] + (size_t)(chunk & ~63) * 16);
        }
    };
    auto stB = [&](int s, int K) {
        int chunk = tid;
        int row = chunk >> 2, slot = chunk & 3;
        int ks = (slot * 8) ^ ((row & 6) << 2);
        gload_lds16(BT + (size_t)(bcol + row) * KTOT + K * 32 + ks,
                    (char*)&Bl[s][0] + (size_t)(chunk & ~63) * 16);
    };

    f32x4 accP[4][4];
    u32   accB[4][4][2];
#pragma unroll
    for (int m = 0; m < 4; ++m)
#pragma unroll
        for (int n = 0; n < 4; ++n) {
            accP[m][n] = (f32x4){0.f, 0.f, 0.f, 0.f};
            accB[m][n][0] = 0u; accB[m][n][1] = 0u;
        }

    auto fold = [&](int e) {
#pragma unroll
        for (int m = 0; m < 4; ++m) {
            int rbase = wm * 64 + m * 16 + jrow;
            float g0 = gLds[rbase + 0][e], g1 = gLds[rbase + 1][e];
            float g2 = gLds[rbase + 2][e], g3 = gLds[rbase + 3][e];
#pragma unroll
            for (int n = 0; n < 4; ++n) {
                u32 p0 = accB[m][n][0];
                float lo0 = __uint_as_float(p0 << 16)         + g0 * accP[m][n][0];
                float hi0 = __uint_as_float(p0 & 0xffff0000u) + g1 * accP[m][n][1];
                accB[m][n][0] = (u32)f2bf(lo0) | ((u32)f2bf(hi0) << 16);
                u32 p1 = accB[m][n][1];
                float lo1 = __uint_as_float(p1 << 16)         + g2 * accP[m][n][2];
                float hi1 = __uint_as_float(p1 & 0xffff0000u) + g3 * accP[m][n][3];
                accB[m][n][1] = (u32)f2bf(lo1) | ((u32)f2bf(hi1) << 16);
                accP[m][n] = (f32x4){0.f, 0.f, 0.f, 0.f};
            }
        }
    };

    auto do_phase = [&](int k, bool issue) {
        const ushort* As = &Al[k & 3][0];
        const ushort* Bs = &Bl[k & 3][0];
        short8 a[4];
#pragma unroll
        for (int m = 0; m < 4; ++m) a[m] = *(const short8*)(As + offA[m]);
        short8 b0 = *(const short8*)(Bs + offB[0]);
        short8 b1 = *(const short8*)(Bs + offB[1]);
        short8 b2 = *(const short8*)(Bs + offB[2]);
        short8 b3 = *(const short8*)(Bs + offB[3]);
        if (issue) { stA((k + 3) & 3, k + 3); stB((k + 3) & 3, k + 3); }
        PH_BAR(); LGKM0();
        __builtin_amdgcn_s_setprio(1);
#pragma unroll
        for (int m = 0; m < 4; ++m) {
            accP[m][0] = __builtin_amdgcn_mfma_f32_16x16x32_bf16(a[m], b0, accP[m][0], 0, 0, 0);
            accP[m][1] = __builtin_amdgcn_mfma_f32_16x16x32_bf16(a[m], b1, accP[m][1], 0, 0, 0);
            accP[m][2] = __builtin_amdgcn_mfma_f32_16x16x32_bf16(a[m], b2, accP[m][2], 0, 0, 0);
            accP[m][3] = __builtin_amdgcn_mfma_f32_16x16x32_bf16(a[m], b3, accP[m][3], 0, 0, 0);
        }
        __builtin_amdgcn_s_setprio(0);
        if ((k & 31) == 31 && k != 255) fold(k >> 5);
    };

    stA(0, 0); stB(0, 0);
    stA(1, 1); stB(1, 1);
    stA(2, 2); stB(2, 2);
    VMCNT6();
    PH_BAR();

    for (int k = 0; k < 253; ++k) {
        do_phase(k, true);
        VMCNT6();
        PH_BAR();
    }
    do_phase(253, false); VMCNT3(); PH_BAR();
    do_phase(254, false); VMCNT0(); PH_BAR();
    do_phase(255, false);

#pragma unroll
    for (int m = 0; m < 4; ++m) {
#pragma unroll
        for (int j = 0; j < 4; ++j) {
            int lrow = wm * 64 + m * 16 + jrow + j;
            int grow = brow + lrow;
            float g8[NE];
#pragma unroll
            for (int e = 0; e < NE; ++e) g8[e] = gLds[lrow][e];
#pragma unroll
            for (int n = 0; n < 4; ++n) {
                int col = bcol + wn * 64 + n * 16 + ro;
                float bias = 0.f;
#pragma unroll
                for (int e = 0; e < NE; ++e) bias = fmaf(g8[e], be[e * DOUT + col], bias);
                u32 p = accB[m][n][j >> 1];
                float base = __uint_as_float((j & 1) ? (p & 0xffff0000u) : (p << 16));
                out[(size_t)grow * DOUT + col] = base + g8[7] * accP[m][n][j] + bias;
            }
        }
    }
}

extern "C" void kernel_launch(void* const* d_in, const int* in_sizes, int n_in,
                              void* d_out, int out_size, void* d_ws, size_t ws_size,
                              hipStream_t stream) {
    const float* x  = (const float*)d_in[0];
    const float* We = (const float*)d_in[1];
    const float* be = (const float*)d_in[2];
    const float* Wg = (const float*)d_in[3];
    const float* bg = (const float*)d_in[4];
    float* out = (float*)d_out;

    char* ws = (char*)d_ws;
    const size_t GB   = 256 * 1024;                       // gate probs
    const size_t BTB  = (size_t)DOUT * KTOT * 2;          // 16 MB
    const size_t AGB  = (size_t)N_TOK * KTOT * 2;         // 128 MB
    const size_t NEED = GB + BTB + AGB;                   // 144.25 MB

    float* gbuf = (float*)ws;
    gate_kernel<<<N_TOK / 4, 256, 0, stream>>>(x, Wg, bg, gbuf);

    if (ws_size >= NEED) {
        ushort* BT = (ushort*)(ws + GB);
        ushort* Ag = (ushort*)(ws + GB + BTB);
        transpose_w_kernel<<<dim3(KTOT / 64, DOUT / 64), 256, 0, stream>>>(We, BT);
        prescale_kernel<<<(N_TOK * 128) / 256, 256, 0, stream>>>(x, gbuf, Ag);
        biasinit_kernel<<<(N_TOK * 256) / 256, 256, 0, stream>>>(gbuf, be, out);
        moe_gemm_ps<<<(N_TOK / BM) * (DOUT / BN), 512, 0, stream>>>(Ag, BT, out);
    } else {
        ushort* xb = (ushort*)(ws + GB);
        ushort* BT = (ushort*)(ws + GB + (size_t)N_TOK * DIN * 2);
        cvt_x_kernel<<<(N_TOK * DIN / 4) / 256, 256, 0, stream>>>(x, xb);
        transpose_w_kernel<<<dim3(KTOT / 64, DOUT / 64), 256, 0, stream>>>(We, BT);
        moe_gemm_fb<<<(N_TOK / BM) * (DOUT / BN), 512, 0, stream>>>(xb, BT, gbuf, be, out);
    }
}